// Round 15
// baseline (67.340 us; speedup 1.0000x reference)
//
#include <hip/hip_runtime.h>

// NCC loss (B=2, C=1, 160^3 f32, 9^3 box window). Two passes + reduce.
// bufA layout: [b][z][y][xg8][48B] where the 48B group = 5 fields x 8B fp8
// (8 x-values each) + 8B pad -> group loads/stores are 3 wide VMEM ops.
// pass_pzx: block=(b,y,x-tile 80,z-chunk 32). Stage x-windowed products
//           (1 unit/thread, prefix over 16) -> bf16 LDS [5][40][80] via
//           ds_write_b128. One barrier. Compute: 8-x threads, 1 z each,
//           9-tap z-window from LDS (uint4 reads) -> 3 stores per group.
// pass_y  : thin y-slide (8-wide, CHY=2); per tap row = 3 loads (was 5).
// finalize: deterministic reduce.

typedef float floatx2 __attribute__((ext_vector_type(2)));

constexpr int W = 160, H = 160, D = 160;
constexpr int SLICE = W * H;
constexpr int NVOX  = W * H * D;
constexpr int BATCH = 2;
constexpr float RW  = 1.0f / 729.0f;

constexpr int NG   = W / 8;              // 20 groups per (z,y) row
constexpr int GB   = 48;                 // bytes per group (40 data + 8 pad)
constexpr int ROWB = NG * GB;            // 960 B per (z,y) row

// pass_pzx geometry
constexpr int TPB_P = 400;               // staging: 1 unit per thread
constexpr int XT    = 80;                // x-tile width
constexpr int NXT   = W / XT;            // 2
constexpr int CZ    = 32;                // z outputs per block
constexpr int NCZ   = D / CZ;            // 5
constexpr int ZS    = CZ + 8;            // 40 staged slices
constexpr int NBLK_P = BATCH * H * NXT * NCZ;    // 3200

// pass_y geometry
constexpr int TPB_Y = 256;
constexpr int XGY   = NG;                // 20 (8-x groups)
constexpr int CHY   = 2, NCHY = H / CHY; // 80
constexpr int NTH_Y = BATCH * D * NCHY * XGY;    // 512,000
constexpr int NBLK_Y = NTH_Y / TPB_Y;            // 2000

// ---- fp8 / bf16 helpers --------------------------------------------------
__device__ inline unsigned int pk4(float a, float b, float c, float d) {
    unsigned int u = 0;
    u = __builtin_amdgcn_cvt_pk_fp8_f32(a, b, u, false);
    u = __builtin_amdgcn_cvt_pk_fp8_f32(c, d, u, true);
    return u;
}
__device__ inline void up8u(unsigned int lo, unsigned int hi, float* o) {
    floatx2 t;
    t = __builtin_amdgcn_cvt_pk_f32_fp8(lo, false); o[0] = t[0]; o[1] = t[1];
    t = __builtin_amdgcn_cvt_pk_f32_fp8(lo, true);  o[2] = t[0]; o[3] = t[1];
    t = __builtin_amdgcn_cvt_pk_f32_fp8(hi, false); o[4] = t[0]; o[5] = t[1];
    t = __builtin_amdgcn_cvt_pk_f32_fp8(hi, true);  o[6] = t[0]; o[7] = t[1];
}
__device__ inline unsigned short f2bf(float f) {
    unsigned int u = __builtin_bit_cast(unsigned int, f);
    u += 0x7fffu + ((u >> 16) & 1u);
    return (unsigned short)(u >> 16);
}
__device__ inline unsigned int bfpack2(float lo, float hi) {
    return (unsigned int)f2bf(lo) | ((unsigned int)f2bf(hi) << 16);
}
__device__ inline float bflo(unsigned int u) {
    return __builtin_bit_cast(float, u << 16);
}
__device__ inline float bfhi(unsigned int u) {
    return __builtin_bit_cast(float, u & 0xffff0000u);
}

// ---- pass 1: x-window at staging (regs) + z-window from LDS --------------
__global__ __launch_bounds__(TPB_P) void pass_pzx(const float* __restrict__ I,
                                                  const float* __restrict__ J,
                                                  unsigned char* __restrict__ outA) {
    __shared__ unsigned short xw[5][ZS][XT];   // bf16, 32000 B

    int blk = blockIdx.x;
    int zc = blk % NCZ;
    int xt = (blk / NCZ) % NXT;
    int y  = (blk / (NCZ * NXT)) % H;
    int b  = blk / (NCZ * NXT * H);
    int tx0 = xt * XT;
    int zbase = zc * CZ - 4;
    const float* Ib = I + (size_t)b * NVOX + y * W;
    const float* Jb = J + (size_t)b * NVOX + y * W;

    // ---- staging: exactly one (slice zs, 8-x) unit per thread ------------
    const float4 Z4 = make_float4(0.f, 0.f, 0.f, 0.f);
    {
        int u = threadIdx.x;             // 0..399 == ZS*10 units
        int zs = u / 10;
        int xu = u % 10;
        int gxs = tx0 + xu * 8;
        int gz = zbase + zs;
        float a[16], c[16];
        if (gz >= 0 && gz < D) {
            const float* ip = Ib + (size_t)gz * SLICE + gxs;
            const float* jp = Jb + (size_t)gz * SLICE + gxs;
            float4 A0 = (gxs >= 4)     ? *(const float4*)(ip - 4) : Z4;
            float4 A1 = *(const float4*)(ip);
            float4 A2 = *(const float4*)(ip + 4);
            float4 A3 = (gxs + 11 < W) ? *(const float4*)(ip + 8) : Z4;
            float4 C0 = (gxs >= 4)     ? *(const float4*)(jp - 4) : Z4;
            float4 C1 = *(const float4*)(jp);
            float4 C2 = *(const float4*)(jp + 4);
            float4 C3 = (gxs + 11 < W) ? *(const float4*)(jp + 8) : Z4;
            float at[16] = {A0.x,A0.y,A0.z,A0.w, A1.x,A1.y,A1.z,A1.w,
                            A2.x,A2.y,A2.z,A2.w, A3.x,A3.y,A3.z,A3.w};
            float ct[16] = {C0.x,C0.y,C0.z,C0.w, C1.x,C1.y,C1.z,C1.w,
                            C2.x,C2.y,C2.z,C2.w, C3.x,C3.y,C3.z,C3.w};
#pragma unroll
            for (int k = 0; k < 16; ++k) { a[k] = at[k]; c[k] = ct[k]; }
        } else {
#pragma unroll
            for (int k = 0; k < 16; ++k) { a[k] = 0.f; c[k] = 0.f; }
        }
#pragma unroll
        for (int f = 0; f < 5; ++f) {
            float v[16];
#pragma unroll
            for (int k = 0; k < 16; ++k) {
                float x = a[k], yv = c[k];
                v[k] = (f == 0) ? x : (f == 1) ? yv :
                       (f == 2) ? x * x : (f == 3) ? yv * yv : x * yv;
            }
            float P[16];
            P[0] = v[0];
#pragma unroll
            for (int k = 1; k < 16; ++k) P[k] = P[k - 1] + v[k];
            float w[8];
            w[0] = P[8];
#pragma unroll
            for (int j = 1; j < 8; ++j) w[j] = P[j + 8] - P[j - 1];
            uint4 pk;
            pk.x = bfpack2(w[0], w[1]);
            pk.y = bfpack2(w[2], w[3]);
            pk.z = bfpack2(w[4], w[5]);
            pk.w = bfpack2(w[6], w[7]);
            *(uint4*)&xw[f][zs][xu * 8] = pk;   // single ds_write_b128
        }
    }

    __syncthreads();

    // ---- compute: 8-x threads, 1 z each, 9-tap z-window over LDS ---------
    if (threadIdx.x < 320) {
        int xu = threadIdx.x % 10;       // 8-x group (tile-local)
        int zl = threadIdx.x / 10;       // 0..31, one z output
        int x0l = xu * 8;

        float acc[5][8];
#pragma unroll
        for (int f = 0; f < 5; ++f)
#pragma unroll
            for (int i = 0; i < 8; ++i) acc[f][i] = 0.f;

#pragma unroll
        for (int k = 0; k < 9; ++k) {
#pragma unroll
            for (int f = 0; f < 5; ++f) {
                uint4 v = *(const uint4*)&xw[f][zl + k][x0l];
                acc[f][0] += bflo(v.x); acc[f][1] += bfhi(v.x);
                acc[f][2] += bflo(v.y); acc[f][3] += bfhi(v.y);
                acc[f][4] += bflo(v.z); acc[f][5] += bfhi(v.z);
                acc[f][6] += bflo(v.w); acc[f][7] += bfhi(v.w);
            }
        }

        int gz = zc * CZ + zl;
        int xg8 = xt * 10 + xu;
        unsigned char* op = outA +
            ((size_t)((b * D + gz) * H + y) * NG + xg8) * GB;
        uint4 st0;
        st0.x = pk4(acc[0][0], acc[0][1], acc[0][2], acc[0][3]);
        st0.y = pk4(acc[0][4], acc[0][5], acc[0][6], acc[0][7]);
        st0.z = pk4(acc[1][0], acc[1][1], acc[1][2], acc[1][3]);
        st0.w = pk4(acc[1][4], acc[1][5], acc[1][6], acc[1][7]);
        uint4 st1;
        st1.x = pk4(acc[2][0], acc[2][1], acc[2][2], acc[2][3]);
        st1.y = pk4(acc[2][4], acc[2][5], acc[2][6], acc[2][7]);
        st1.z = pk4(acc[3][0], acc[3][1], acc[3][2], acc[3][3]);
        st1.w = pk4(acc[3][4], acc[3][5], acc[3][6], acc[3][7]);
        uint2 st2;
        st2.x = pk4(acc[4][0], acc[4][1], acc[4][2], acc[4][3]);
        st2.y = pk4(acc[4][4], acc[4][5], acc[4][6], acc[4][7]);
        *(uint4*)(op)      = st0;
        *(uint4*)(op + 16) = st1;
        *(uint2*)(op + 32) = st2;
    }
}

// ---- pass 2: thin y-slide + cc + reduce (3 loads per tap row) ------------
__global__ __launch_bounds__(TPB_Y) void pass_y(const unsigned char* __restrict__ A,
                                                double* __restrict__ partials) {
    int tid = threadIdx.x;
    int t = blockIdx.x * TPB_Y + tid;
    int xg = t % XGY;
    int tup = t / XGY;
    int yc = tup % NCHY;
    int z  = (tup / NCHY) % D;
    int b  = tup / (NCHY * D);
    const unsigned char* __restrict__ base =
        A + ((size_t)(b * D + z) * H * NG + xg) * GB;
    int y0 = yc * CHY;

    float s[5][8];
#pragma unroll
    for (int f = 0; f < 5; ++f)
#pragma unroll
        for (int i = 0; i < 8; ++i) s[f][i] = 0.f;

    auto tapRow = [&](int yy, float sgn) {
        const unsigned char* rp = base + (size_t)yy * ROWB;
        uint4 L0 = *(const uint4*)(rp);
        uint4 L1 = *(const uint4*)(rp + 16);
        uint2 L2 = *(const uint2*)(rp + 32);
        float u[8];
        up8u(L0.x, L0.y, u);
#pragma unroll
        for (int i = 0; i < 8; ++i) s[0][i] += sgn * u[i];
        up8u(L0.z, L0.w, u);
#pragma unroll
        for (int i = 0; i < 8; ++i) s[1][i] += sgn * u[i];
        up8u(L1.x, L1.y, u);
#pragma unroll
        for (int i = 0; i < 8; ++i) s[2][i] += sgn * u[i];
        up8u(L1.z, L1.w, u);
#pragma unroll
        for (int i = 0; i < 8; ++i) s[3][i] += sgn * u[i];
        up8u(L2.x, L2.y, u);
#pragma unroll
        for (int i = 0; i < 8; ++i) s[4][i] += sgn * u[i];
    };

    int ylo = y0 - 4 < 0 ? 0 : y0 - 4;
    int yhi = y0 + 4 > H - 1 ? H - 1 : y0 + 4;
    for (int yy = ylo; yy <= yhi; ++yy) tapRow(yy, 1.f);

    double acc = 0.0;
#pragma unroll
    for (int dy = 0; dy < CHY; ++dy) {
        float rowcc = 0.f;
#pragma unroll
        for (int i = 0; i < 8; ++i) {
            float Is = s[0][i], Js = s[1][i];
            float I2s = s[2][i], J2s = s[3][i], IJs = s[4][i];
            float tI = RW * Is;
            float cross = __builtin_fmaf(-tI, Js, IJs);
            float Iv    = __builtin_fmaf(-tI, Is, I2s);
            float Jv    = __builtin_fmaf(-(RW * Js), Js, J2s);
            float den   = __builtin_fmaf(Iv, Jv, 1e-5f);
            rowcc = __builtin_fmaf(cross * cross, __builtin_amdgcn_rcpf(den), rowcc);
        }
        acc += (double)rowcc;

        int ye = y0 + dy + 5, yl = y0 + dy - 4;
        if (ye < H) tapRow(ye, 1.f);
        if (yl >= 0) tapRow(yl, -1.f);
    }

    // deterministic block reduction
#pragma unroll
    for (int off = 32; off > 0; off >>= 1) acc += __shfl_down(acc, off);
    __shared__ double sm[TPB_Y / 64];
    if ((tid & 63) == 0) sm[tid >> 6] = acc;
    __syncthreads();
    if (tid == 0) {
        double tt = 0.0;
#pragma unroll
        for (int i = 0; i < TPB_Y / 64; ++i) tt += sm[i];
        partials[blockIdx.x] = tt;
    }
}

// ---- final deterministic reduce ------------------------------------------
__global__ __launch_bounds__(256) void finalize(const double* __restrict__ p,
                                                float* __restrict__ out) {
    double v = 0.0;
    for (int i = threadIdx.x; i < NBLK_Y; i += 256) v += p[i];
#pragma unroll
    for (int off = 32; off > 0; off >>= 1) v += __shfl_down(v, off);
    __shared__ double sm[4];
    int lane = threadIdx.x & 63, wid = threadIdx.x >> 6;
    if (lane == 0) sm[wid] = v;
    __syncthreads();
    if (threadIdx.x == 0) {
        double tt = 0.0;
#pragma unroll
        for (int i = 0; i < 4; ++i) tt += sm[i];
        out[0] = (float)(1.0 - tt / (double)((double)BATCH * (double)NVOX));
    }
}

extern "C" void kernel_launch(void* const* d_in, const int* in_sizes, int n_in,
                              void* d_out, int out_size, void* d_ws, size_t ws_size,
                              hipStream_t stream) {
    const float* I = (const float*)d_in[0];
    const float* J = (const float*)d_in[1];
    float* out = (float*)d_out;

    // ws: bufA (B*D*H*20*48 = 49.2 MB) | partials (NBLK_Y f64)
    size_t bufsz = ((size_t)BATCH * D * H * NG * GB + 255) / 256 * 256;
    unsigned char* bufA = (unsigned char*)d_ws;
    double* partials = (double*)(bufA + bufsz);

    pass_pzx<<<NBLK_P, TPB_P, 0, stream>>>(I, J, bufA);
    pass_y<<<NBLK_Y, TPB_Y, 0, stream>>>(bufA, partials);
    finalize<<<1, 256, 0, stream>>>(partials, out);
}

// Round 16
// 60.226 us; speedup vs baseline: 1.1181x; 1.1181x over previous
//
#include <hip/hip_runtime.h>

// NCC loss (B=2, C=1, 160^3 f32, 9^3 box window). Two passes + reduce.
// pass_pzx: block=(b,y,xt 80,zc 80). Staging: x-windowed products (prefix
//           over 16 per 8-x unit) -> fp8 LDS [5][88][80] (35.2 KB), one
//           barrier. Compute: 400 threads (20 xg x 20 zl), each slides a
//           9-tap z-window across 4 z outputs (3.75 taps/z, 4-B taps)
//           -> fp8 bufA [b][z][y][f][x].
// pass_y  : thin y-slide (8-wide, CHY=2) + cc + reduction (proven R10).
// finalize: deterministic reduce.

typedef float floatx2 __attribute__((ext_vector_type(2)));

constexpr int W = 160, H = 160, D = 160;
constexpr int SLICE = W * H;
constexpr int NVOX  = W * H * D;
constexpr int BATCH = 2;
constexpr int FROW  = 5 * W;             // 800 B per (b,z,y) row-group
constexpr float RW  = 1.0f / 729.0f;

// pass_pzx geometry
constexpr int TPB_P = 400;
constexpr int XT    = 80;                // x-tile width
constexpr int NXT   = W / XT;            // 2
constexpr int CZ    = 80;                // z outputs per block
constexpr int NCZ   = D / CZ;            // 2
constexpr int ZS    = CZ + 8;            // 88 staged slices
constexpr int NUNITS = ZS * 10;          // 880 staging units
constexpr int NBLK_P = BATCH * H * NXT * NCZ;    // 1280

// pass_y geometry (proven R10)
constexpr int TPB_Y = 256;
constexpr int XGY   = W / 8;             // 20
constexpr int CHY   = 2, NCHY = H / CHY; // 80
constexpr int NTH_Y = BATCH * D * NCHY * XGY;    // 512,000
constexpr int NBLK_Y = NTH_Y / TPB_Y;            // 2000

// ---- fp8 helpers (HW cvt, OCP e4m3) --------------------------------------
__device__ inline unsigned int pk4(float a, float b, float c, float d) {
    unsigned int u = 0;
    u = __builtin_amdgcn_cvt_pk_fp8_f32(a, b, u, false);
    u = __builtin_amdgcn_cvt_pk_fp8_f32(c, d, u, true);
    return u;
}
__device__ inline void up4(unsigned int v, float* o) {
    floatx2 t;
    t = __builtin_amdgcn_cvt_pk_f32_fp8(v, false); o[0] = t[0]; o[1] = t[1];
    t = __builtin_amdgcn_cvt_pk_f32_fp8(v, true);  o[2] = t[0]; o[3] = t[1];
}
__device__ inline void up8(uint2 v, float* o) {
    up4(v.x, o); up4(v.y, o + 4);
}

// ---- pass 1: x-window at staging -> fp8 LDS; 4-z sliding z-window --------
__global__ __launch_bounds__(TPB_P) void pass_pzx(const float* __restrict__ I,
                                                  const float* __restrict__ J,
                                                  unsigned char* __restrict__ outA) {
    __shared__ unsigned char xw[5][ZS][XT];    // fp8, 35,200 B

    int blk = blockIdx.x;
    int zc = blk % NCZ;
    int xt = (blk / NCZ) % NXT;
    int y  = (blk / (NCZ * NXT)) % H;
    int b  = blk / (NCZ * NXT * H);
    int tx0 = xt * XT;
    int zbase = zc * CZ - 4;
    const float* Ib = I + (size_t)b * NVOX + y * W;
    const float* Jb = J + (size_t)b * NVOX + y * W;

    // ---- staging: 880 (slice, 8-x) units over 400 threads ----------------
    const float4 Z4 = make_float4(0.f, 0.f, 0.f, 0.f);
    for (int u = threadIdx.x; u < NUNITS; u += TPB_P) {
        int zs = u / 10;
        int xu = u % 10;
        int gxs = tx0 + xu * 8;
        int gz = zbase + zs;
        float a[16], c[16];
        if (gz >= 0 && gz < D) {
            const float* ip = Ib + (size_t)gz * SLICE + gxs;
            const float* jp = Jb + (size_t)gz * SLICE + gxs;
            float4 A0 = (gxs >= 4)     ? *(const float4*)(ip - 4) : Z4;
            float4 A1 = *(const float4*)(ip);
            float4 A2 = *(const float4*)(ip + 4);
            float4 A3 = (gxs + 11 < W) ? *(const float4*)(ip + 8) : Z4;
            float4 C0 = (gxs >= 4)     ? *(const float4*)(jp - 4) : Z4;
            float4 C1 = *(const float4*)(jp);
            float4 C2 = *(const float4*)(jp + 4);
            float4 C3 = (gxs + 11 < W) ? *(const float4*)(jp + 8) : Z4;
            float at[16] = {A0.x,A0.y,A0.z,A0.w, A1.x,A1.y,A1.z,A1.w,
                            A2.x,A2.y,A2.z,A2.w, A3.x,A3.y,A3.z,A3.w};
            float ct[16] = {C0.x,C0.y,C0.z,C0.w, C1.x,C1.y,C1.z,C1.w,
                            C2.x,C2.y,C2.z,C2.w, C3.x,C3.y,C3.z,C3.w};
#pragma unroll
            for (int k = 0; k < 16; ++k) { a[k] = at[k]; c[k] = ct[k]; }
        } else {
#pragma unroll
            for (int k = 0; k < 16; ++k) { a[k] = 0.f; c[k] = 0.f; }
        }
#pragma unroll
        for (int f = 0; f < 5; ++f) {
            float v[16];
#pragma unroll
            for (int k = 0; k < 16; ++k) {
                float x = a[k], yv = c[k];
                v[k] = (f == 0) ? x : (f == 1) ? yv :
                       (f == 2) ? x * x : (f == 3) ? yv * yv : x * yv;
            }
            float P[16];
            P[0] = v[0];
#pragma unroll
            for (int k = 1; k < 16; ++k) P[k] = P[k - 1] + v[k];
            float w[8];
            w[0] = P[8];
#pragma unroll
            for (int j = 1; j < 8; ++j) w[j] = P[j + 8] - P[j - 1];
            uint2 pk;
            pk.x = pk4(w[0], w[1], w[2], w[3]);
            pk.y = pk4(w[4], w[5], w[6], w[7]);
            *(uint2*)&xw[f][zs][xu * 8] = pk;
        }
    }

    __syncthreads();

    // ---- compute: 20 xg (4x) x 20 zl (4z each), sliding 9-tap z-window ---
    {
        int xg = threadIdx.x % 20;
        int zl = threadIdx.x / 20;       // 0..19
        int x0l = xg * 4;
        int zo0 = zl * 4;                // lds slice index of first output

        float acc[5][4];
#pragma unroll
        for (int f = 0; f < 5; ++f)
#pragma unroll
            for (int i = 0; i < 4; ++i) acc[f][i] = 0.f;

        // init window: lds slices zo0 .. zo0+8
#pragma unroll
        for (int k = 0; k < 9; ++k) {
#pragma unroll
            for (int f = 0; f < 5; ++f) {
                unsigned int v = *(const unsigned int*)&xw[f][zo0 + k][x0l];
                float u[4]; up4(v, u);
                acc[f][0] += u[0]; acc[f][1] += u[1];
                acc[f][2] += u[2]; acc[f][3] += u[3];
            }
        }

        int gz0 = zc * CZ + zo0;
        unsigned char* op = outA + ((size_t)(b * D + gz0) * H + y) * FROW + tx0 + x0l;
#pragma unroll
        for (int q = 0; q < 4; ++q) {
#pragma unroll
            for (int f = 0; f < 5; ++f)
                *(unsigned int*)(op + f * W) =
                    pk4(acc[f][0], acc[f][1], acc[f][2], acc[f][3]);
            if (q < 3) {
#pragma unroll
                for (int f = 0; f < 5; ++f) {
                    unsigned int ve = *(const unsigned int*)&xw[f][zo0 + 9 + q][x0l];
                    unsigned int vl = *(const unsigned int*)&xw[f][zo0 + q][x0l];
                    float ue[4], ul[4];
                    up4(ve, ue); up4(vl, ul);
                    acc[f][0] += ue[0] - ul[0]; acc[f][1] += ue[1] - ul[1];
                    acc[f][2] += ue[2] - ul[2]; acc[f][3] += ue[3] - ul[3];
                }
                op += (size_t)H * FROW;
            }
        }
    }
}

// ---- pass 2: thin y-slide + cc + reduce (proven R10) ---------------------
__global__ __launch_bounds__(TPB_Y) void pass_y(const unsigned char* __restrict__ A,
                                                double* __restrict__ partials) {
    int tid = threadIdx.x;
    int t = blockIdx.x * TPB_Y + tid;
    int xg = t % XGY;
    int tup = t / XGY;
    int yc = tup % NCHY;
    int z  = (tup / NCHY) % D;
    int b  = tup / (NCHY * D);
    int x0 = xg * 8;
    const unsigned char* __restrict__ base =
        A + (size_t)(b * D + z) * H * FROW + x0;
    int y0 = yc * CHY;

    float s[5][8];
#pragma unroll
    for (int f = 0; f < 5; ++f)
#pragma unroll
        for (int i = 0; i < 8; ++i) s[f][i] = 0.f;

    int ylo = y0 - 4 < 0 ? 0 : y0 - 4;
    int yhi = y0 + 4 > H - 1 ? H - 1 : y0 + 4;
    for (int yy = ylo; yy <= yhi; ++yy) {
        const unsigned char* rp = base + (size_t)yy * FROW;
#pragma unroll
        for (int f = 0; f < 5; ++f) {
            uint2 v = *(const uint2*)(rp + f * W);
            float u[8]; up8(v, u);
#pragma unroll
            for (int i = 0; i < 8; ++i) s[f][i] += u[i];
        }
    }

    double acc = 0.0;
#pragma unroll
    for (int dy = 0; dy < CHY; ++dy) {
        int ye = y0 + dy + 5, yl = y0 + dy - 4;
        bool he = ye < H, hl = yl >= 0;
        uint2 pe[5], pl[5];
        const unsigned char* pre = base + (size_t)(he ? ye : 0) * FROW;
        const unsigned char* prl = base + (size_t)(hl ? yl : 0) * FROW;
#pragma unroll
        for (int f = 0; f < 5; ++f) {
            pe[f] = he ? *(const uint2*)(pre + f * W) : make_uint2(0u, 0u);
            pl[f] = hl ? *(const uint2*)(prl + f * W) : make_uint2(0u, 0u);
        }

        float rowcc = 0.f;
#pragma unroll
        for (int i = 0; i < 8; ++i) {
            float Is = s[0][i], Js = s[1][i];
            float I2s = s[2][i], J2s = s[3][i], IJs = s[4][i];
            float tI = RW * Is;
            float cross = __builtin_fmaf(-tI, Js, IJs);
            float Iv    = __builtin_fmaf(-tI, Is, I2s);
            float Jv    = __builtin_fmaf(-(RW * Js), Js, J2s);
            float den   = __builtin_fmaf(Iv, Jv, 1e-5f);
            rowcc = __builtin_fmaf(cross * cross, __builtin_amdgcn_rcpf(den), rowcc);
        }
        acc += (double)rowcc;

#pragma unroll
        for (int f = 0; f < 5; ++f) {
            float ue[8], ul[8];
            up8(pe[f], ue); up8(pl[f], ul);
#pragma unroll
            for (int i = 0; i < 8; ++i) s[f][i] += ue[i] - ul[i];
        }
    }

    // deterministic block reduction
#pragma unroll
    for (int off = 32; off > 0; off >>= 1) acc += __shfl_down(acc, off);
    __shared__ double sm[TPB_Y / 64];
    if ((tid & 63) == 0) sm[tid >> 6] = acc;
    __syncthreads();
    if (tid == 0) {
        double tt = 0.0;
#pragma unroll
        for (int i = 0; i < TPB_Y / 64; ++i) tt += sm[i];
        partials[blockIdx.x] = tt;
    }
}

// ---- final deterministic reduce ------------------------------------------
__global__ __launch_bounds__(256) void finalize(const double* __restrict__ p,
                                                float* __restrict__ out) {
    double v = 0.0;
    for (int i = threadIdx.x; i < NBLK_Y; i += 256) v += p[i];
#pragma unroll
    for (int off = 32; off > 0; off >>= 1) v += __shfl_down(v, off);
    __shared__ double sm[4];
    int lane = threadIdx.x & 63, wid = threadIdx.x >> 6;
    if (lane == 0) sm[wid] = v;
    __syncthreads();
    if (threadIdx.x == 0) {
        double tt = 0.0;
#pragma unroll
        for (int i = 0; i < 4; ++i) tt += sm[i];
        out[0] = (float)(1.0 - tt / (double)((double)BATCH * (double)NVOX));
    }
}

extern "C" void kernel_launch(void* const* d_in, const int* in_sizes, int n_in,
                              void* d_out, int out_size, void* d_ws, size_t ws_size,
                              hipStream_t stream) {
    const float* I = (const float*)d_in[0];
    const float* J = (const float*)d_in[1];
    float* out = (float*)d_out;

    // ws: bufA (41 MB fp8, [b][z][y][f][x]) | partials (NBLK_Y f64)
    size_t bufsz = ((size_t)BATCH * 5 * NVOX + 255) / 256 * 256;
    unsigned char* bufA = (unsigned char*)d_ws;
    double* partials = (double*)(bufA + bufsz);

    pass_pzx<<<NBLK_P, TPB_P, 0, stream>>>(I, J, bufA);
    pass_y<<<NBLK_Y, TPB_Y, 0, stream>>>(bufA, partials);
    finalize<<<1, 256, 0, stream>>>(partials, out);
}